// Round 3
// baseline (156.963 us; speedup 1.0000x reference)
//
#include <hip/hip_runtime.h>
#include <hip/hip_bf16.h>

// out[e,i] = sum_j (e@W1+b1)[e, i*16+j] * h[e,j]  +  (e@W2+b2)[e,i]
// One bf16 MFMA GEMM over K=576 per 16-edge tile (18x mfma_f32_16x16x32_bf16).
// K-mapping (same placement function on A and B sides => any HW permutation cancels):
//   main block kk=0..15, slot s=(lane>>4)*8+t:  (d=s, j=kk)
//     A[r,s] = e[edge_r, s] * h[edge_r, kk]     B[s, i=r] = W1[s*256 + r*16 + kk]
//   block 16: A = e[edge, s],                   B = W2[s*16 + r]
//   block 17: s<16: A=h[edge,s], B=b1[r*16+s]; s==16: A=1, B=b2[r]; else 0
// D fragment == output (col=lane&15=i, row=(lane>>4)*4+q=edge-in-tile).
// Value path: __float2bfloat16 only (R0-verified). No inline asm, no unions on frags.

using bf16x8 = __attribute__((ext_vector_type(8))) short;
using f32x4  = __attribute__((ext_vector_type(4))) float;

static __device__ __forceinline__ short f2bf(float x) {
    union { __hip_bfloat16 b; short s; } u;
    u.b = __float2bfloat16(x);
    return u.s;
}

__global__ void __launch_bounds__(256) msg_kernel(
    const float* __restrict__ hptr, const float* __restrict__ eptr,
    const float* __restrict__ W1,   const float* __restrict__ b1,
    const float* __restrict__ W2,   const float* __restrict__ b2,
    float* __restrict__ out, int E)
{
    const int lane = threadIdx.x & 63;
    const int g    = lane >> 4;        // K-group (0..3); this lane's d-range = [g*8, g*8+8)
    const int r    = lane & 15;        // A row (edge-in-tile) == B/D col (output i)

    // ---- B fragments: edge-invariant, built once into registers ----
    bf16x8 Bf[18];
    #pragma unroll
    for (int t = 0; t < 8; ++t) {      // per-t to keep live floats small
        const int d = g * 8 + t;
        const float4* wp = (const float4*)(W1 + (size_t)d * 256 + r * 16);
        const float4 w0 = wp[0], w1 = wp[1], w2 = wp[2], w3 = wp[3];
        const float wv[16] = {w0.x, w0.y, w0.z, w0.w, w1.x, w1.y, w1.z, w1.w,
                              w2.x, w2.y, w2.z, w2.w, w3.x, w3.y, w3.z, w3.w};
        #pragma unroll
        for (int kk = 0; kk < 16; ++kk) Bf[kk][t] = f2bf(wv[kk]);
    }
    #pragma unroll
    for (int t = 0; t < 8; ++t) {      // W2 block
        Bf[16][t] = f2bf(W2[(g * 8 + t) * 16 + r]);
    }
    #pragma unroll
    for (int t = 0; t < 8; ++t) {      // b1/b2 block
        const int s = g * 8 + t;
        float v;
        if (s < 16)       v = b1[r * 16 + s];
        else if (s == 16) v = b2[r];
        else              v = 0.0f;
        Bf[17][t] = f2bf(v);
    }

    const int ntiles = (E + 15) >> 4;
    const int nwaves = (gridDim.x * blockDim.x) >> 6;
    const int wid    = (blockIdx.x * blockDim.x + threadIdx.x) >> 6;

    int tile = wid;
    if (tile >= ntiles) return;

    // ---- prologue loads (tile 0 of this wave) ----
    int ce = tile * 16 + r;  if (ce >= E) ce = E - 1;
    {
        // nothing else
    }
    const float4* ep0 = (const float4*)(eptr + (size_t)ce * 32 + g * 8);
    float4 ce0 = ep0[0], ce1 = ep0[1];
    const float4* hp0 = (const float4*)(hptr + (size_t)ce * 16);
    float4 ch0 = hp0[0], ch1 = hp0[1], ch2 = hp0[2], ch3 = hp0[3];

    while (tile < ntiles) {
        const int nxt  = tile + nwaves;
        const bool hasn = nxt < ntiles;
        int cen = hasn ? (nxt * 16 + r) : ce;
        if (cen >= E) cen = E - 1;

        // ---- issue next tile's loads (independent of current compute) ----
        const float4* epn = (const float4*)(eptr + (size_t)cen * 32 + g * 8);
        float4 ne0 = epn[0], ne1 = epn[1];
        const float4* hpn = (const float4*)(hptr + (size_t)cen * 16);
        float4 nh0 = hpn[0], nh1 = hpn[1], nh2 = hpn[2], nh3 = hpn[3];

        // ---- compute current tile ----
        const float ev[8]  = {ce0.x, ce0.y, ce0.z, ce0.w, ce1.x, ce1.y, ce1.z, ce1.w};
        const float hv[16] = {ch0.x, ch0.y, ch0.z, ch0.w, ch1.x, ch1.y, ch1.z, ch1.w,
                              ch2.x, ch2.y, ch2.z, ch2.w, ch3.x, ch3.y, ch3.z, ch3.w};

        f32x4 acc0 = {0.0f, 0.0f, 0.0f, 0.0f};
        f32x4 acc1 = {0.0f, 0.0f, 0.0f, 0.0f};

        #pragma unroll
        for (int kk = 0; kk < 16; ++kk) {
            const float s = hv[kk];
            bf16x8 a;
            #pragma unroll
            for (int t = 0; t < 8; ++t) a[t] = f2bf(s * ev[t]);
            if (kk & 1)
                acc1 = __builtin_amdgcn_mfma_f32_16x16x32_bf16(a, Bf[kk], acc1, 0, 0, 0);
            else
                acc0 = __builtin_amdgcn_mfma_f32_16x16x32_bf16(a, Bf[kk], acc0, 0, 0, 0);
        }
        {   // W2 block: A = e[edge, s]
            bf16x8 a;
            #pragma unroll
            for (int t = 0; t < 8; ++t) a[t] = f2bf(ev[t]);
            acc0 = __builtin_amdgcn_mfma_f32_16x16x32_bf16(a, Bf[16], acc0, 0, 0, 0);
        }
        {   // b1/b2 block: A = h[edge,s] for s<16 (g<2), A=1 at s==16, else 0
            bf16x8 a;
            #pragma unroll
            for (int t = 0; t < 8; ++t) {
                const float hsel = (g & 1) ? hv[8 + t] : hv[t];   // static indices
                const float v = (g < 2) ? hsel : ((g == 2 && t == 0) ? 1.0f : 0.0f);
                a[t] = f2bf(v);
            }
            acc1 = __builtin_amdgcn_mfma_f32_16x16x32_bf16(a, Bf[17], acc1, 0, 0, 0);
        }

        // D: col = r = i, row = g*4 + q = edge-in-tile
        const int rowbase = tile * 16 + g * 4;
        #pragma unroll
        for (int q = 0; q < 4; ++q) {
            const int row = rowbase + q;
            if (row < E) out[(size_t)row * 16 + r] = acc0[q] + acc1[q];
        }

        // ---- rotate ----
        tile = nxt;
        ce   = cen;
        ce0 = ne0; ce1 = ne1;
        ch0 = nh0; ch1 = nh1; ch2 = nh2; ch3 = nh3;
    }
}

extern "C" void kernel_launch(void* const* d_in, const int* in_sizes, int n_in,
                              void* d_out, int out_size, void* d_ws, size_t ws_size,
                              hipStream_t stream) {
    const float* h  = (const float*)d_in[0];
    const float* e  = (const float*)d_in[1];
    const float* W1 = (const float*)d_in[2];
    const float* b1 = (const float*)d_in[3];
    const float* W2 = (const float*)d_in[4];
    const float* b2 = (const float*)d_in[5];
    float* out = (float*)d_out;

    const int E = in_sizes[0] / 16;   // h is [E,16]

    dim3 grid(2048), block(256);
    hipLaunchKernelGGL(msg_kernel, grid, block, 0, stream,
                       h, e, W1, b1, W2, b2, out, E);
}

// Round 4
// 124.903 us; speedup vs baseline: 1.2567x; 1.2567x over previous
//
#include <hip/hip_runtime.h>
#include <hip/hip_bf16.h>

// out[e,i] = sum_j (e@W1+b1)[e, i*16+j] * h[e,j]  +  (e@W2+b2)[e,i]
// One bf16 MFMA GEMM over K=576 per 16-edge tile (18x mfma_f32_16x16x32_bf16).
// K-mapping (same placement function on A and B sides):
//   main block kk=0..15, slot s=(lane>>4)*8+t:  (d=s, j=kk)
//     A[r,s] = e[edge_r, s] * h[edge_r, kk]     B[s, i=r] = W1[s*256 + r*16 + kk]
//   block 16: A = e[edge, s],                   B = W2[s*16 + r]
//   block 17: s<16: A=h[edge,s], B=b1[r*16+s]; s==16: A=1, B=b2[r]; else 0
// bf16 conversion in the hot loop: bits+0x8000 (RN, ties-away) + v_perm_b32 pack
// (2 values in 3 VALU ops vs ~10 for 2x software RNE). NO local arrays anywhere
// (R2's float[16] got PromoteAlloca'd into LDS: 16 KB + 1.5e7 bank conflicts).

using bf16x8 = __attribute__((ext_vector_type(8))) short;
using f32x4  = __attribute__((ext_vector_type(4))) float;
using f32x2  = __attribute__((ext_vector_type(2))) float;
using u32x4  = __attribute__((ext_vector_type(4))) unsigned int;

static __device__ __forceinline__ short f2bf(float x) {   // one-time B build only
    union { __hip_bfloat16 b; short s; } u;
    u.b = __float2bfloat16(x);
    return u.s;
}

// pack bf16(lo), bf16(hi) -> u32 {hi16(hi+0x8000), hi16(lo+0x8000)}
static __device__ __forceinline__ unsigned int bfpack(float lo, float hi) {
    unsigned int a = __builtin_bit_cast(unsigned int, lo) + 0x8000u;
    unsigned int b = __builtin_bit_cast(unsigned int, hi) + 0x8000u;
    // v_perm pool: S0=b -> byte idx 4..7, S1=a -> idx 0..3.
    // D bytes [a.b2, a.b3, b.b2, b.b3] => D[15:0]=a[31:16], D[31:16]=b[31:16]
    return __builtin_amdgcn_perm(b, a, 0x07060302u);
}
static __device__ __forceinline__ unsigned int bfpack2(f32x2 v) { return bfpack(v[0], v[1]); }

static __device__ __forceinline__ bf16x8 mkfrag(unsigned int x0, unsigned int x1,
                                                unsigned int x2, unsigned int x3) {
    u32x4 u = {x0, x1, x2, x3};
    return __builtin_bit_cast(bf16x8, u);
}

__global__ void __launch_bounds__(256) msg_kernel(
    const float* __restrict__ hptr, const float* __restrict__ eptr,
    const float* __restrict__ W1,   const float* __restrict__ b1,
    const float* __restrict__ W2,   const float* __restrict__ b2,
    float* __restrict__ out, int E)
{
    const int lane = threadIdx.x & 63;
    const int g    = lane >> 4;        // K-group (0..3); lane's d-range = [g*8, g*8+8)
    const int r    = lane & 15;        // A row (edge-in-tile) == B/D col (output i)

    // ---- B fragments: edge-invariant, built once (software cvt fine here) ----
    bf16x8 Bf[18];
    #pragma unroll
    for (int t = 0; t < 8; ++t) {
        const int d = g * 8 + t;
        const float4* wp = (const float4*)(W1 + (size_t)d * 256 + r * 16);
        const float4 w0 = wp[0], w1 = wp[1], w2 = wp[2], w3 = wp[3];
        Bf[ 0][t] = f2bf(w0.x); Bf[ 1][t] = f2bf(w0.y); Bf[ 2][t] = f2bf(w0.z); Bf[ 3][t] = f2bf(w0.w);
        Bf[ 4][t] = f2bf(w1.x); Bf[ 5][t] = f2bf(w1.y); Bf[ 6][t] = f2bf(w1.z); Bf[ 7][t] = f2bf(w1.w);
        Bf[ 8][t] = f2bf(w2.x); Bf[ 9][t] = f2bf(w2.y); Bf[10][t] = f2bf(w2.z); Bf[11][t] = f2bf(w2.w);
        Bf[12][t] = f2bf(w3.x); Bf[13][t] = f2bf(w3.y); Bf[14][t] = f2bf(w3.z); Bf[15][t] = f2bf(w3.w);
        Bf[16][t] = f2bf(W2[d * 16 + r]);
        float v;
        if (d < 16)       v = b1[r * 16 + d];
        else if (d == 16) v = b2[r];
        else              v = 0.0f;
        Bf[17][t] = f2bf(v);
    }

    const int ntiles = (E + 15) >> 4;
    const int nwaves = (gridDim.x * blockDim.x) >> 6;
    const int wid    = (blockIdx.x * blockDim.x + threadIdx.x) >> 6;

    int tile = wid;
    if (tile >= ntiles) return;

    int ce = tile * 16 + r;  if (ce >= E) ce = E - 1;
    const float4* ep0 = (const float4*)(eptr + (size_t)ce * 32 + g * 8);
    float4 ce0 = ep0[0], ce1 = ep0[1];
    const float4* hp0 = (const float4*)(hptr + (size_t)ce * 16);
    float4 ch0 = hp0[0], ch1 = hp0[1], ch2 = hp0[2], ch3 = hp0[3];

    while (tile < ntiles) {
        const int nxt = tile + nwaves;
        int cen = (nxt < ntiles) ? (nxt * 16 + r) : ce;
        if (cen >= E) cen = E - 1;

        // ---- next tile's loads, issued before current compute ----
        const float4* epn = (const float4*)(eptr + (size_t)cen * 32 + g * 8);
        float4 ne0 = epn[0], ne1 = epn[1];
        const float4* hpn = (const float4*)(hptr + (size_t)cen * 16);
        float4 nh0 = hpn[0], nh1 = hpn[1], nh2 = hpn[2], nh3 = hpn[3];

        // ---- current tile compute (no arrays; all names static) ----
        const f32x2 e01 = {ce0.x, ce0.y}, e23 = {ce0.z, ce0.w};
        const f32x2 e45 = {ce1.x, ce1.y}, e67 = {ce1.z, ce1.w};

        f32x4 acc0 = {0.0f, 0.0f, 0.0f, 0.0f};
        f32x4 acc1 = {0.0f, 0.0f, 0.0f, 0.0f};

#define MB(KK, S, ACC) { \
        const f32x2 p0 = e01 * (S), p1 = e23 * (S), p2 = e45 * (S), p3 = e67 * (S); \
        const bf16x8 a = mkfrag(bfpack2(p0), bfpack2(p1), bfpack2(p2), bfpack2(p3)); \
        ACC = __builtin_amdgcn_mfma_f32_16x16x32_bf16(a, Bf[KK], ACC, 0, 0, 0); }

        MB( 0, ch0.x, acc0) MB( 1, ch0.y, acc1) MB( 2, ch0.z, acc0) MB( 3, ch0.w, acc1)
        MB( 4, ch1.x, acc0) MB( 5, ch1.y, acc1) MB( 6, ch1.z, acc0) MB( 7, ch1.w, acc1)
        MB( 8, ch2.x, acc0) MB( 9, ch2.y, acc1) MB(10, ch2.z, acc0) MB(11, ch2.w, acc1)
        MB(12, ch3.x, acc0) MB(13, ch3.y, acc1) MB(14, ch3.z, acc0) MB(15, ch3.w, acc1)
#undef MB

        {   // block 16: A = e[edge, s]
            const bf16x8 a = mkfrag(bfpack2(e01), bfpack2(e23), bfpack2(e45), bfpack2(e67));
            acc0 = __builtin_amdgcn_mfma_f32_16x16x32_bf16(a, Bf[16], acc0, 0, 0, 0);
        }
        {   // block 17: A = h[edge, s] for s<16; 1 at s==16; else 0
            const float v0 = (g == 0) ? ch0.x : (g == 1) ? ch2.x : (g == 2) ? 1.0f : 0.0f;
            const float v1 = (g == 0) ? ch0.y : (g == 1) ? ch2.y : 0.0f;
            const float v2 = (g == 0) ? ch0.z : (g == 1) ? ch2.z : 0.0f;
            const float v3 = (g == 0) ? ch0.w : (g == 1) ? ch2.w : 0.0f;
            const float v4 = (g == 0) ? ch1.x : (g == 1) ? ch3.x : 0.0f;
            const float v5 = (g == 0) ? ch1.y : (g == 1) ? ch3.y : 0.0f;
            const float v6 = (g == 0) ? ch1.z : (g == 1) ? ch3.z : 0.0f;
            const float v7 = (g == 0) ? ch1.w : (g == 1) ? ch3.w : 0.0f;
            const bf16x8 a = mkfrag(bfpack(v0, v1), bfpack(v2, v3),
                                    bfpack(v4, v5), bfpack(v6, v7));
            acc1 = __builtin_amdgcn_mfma_f32_16x16x32_bf16(a, Bf[17], acc1, 0, 0, 0);
        }

        // D: col = r = i, row = g*4 + q = edge-in-tile
        const int rowbase = tile * 16 + g * 4;
        #pragma unroll
        for (int q = 0; q < 4; ++q) {
            const int row = rowbase + q;
            if (row < E) out[(size_t)row * 16 + r] = acc0[q] + acc1[q];
        }

        // ---- rotate pipeline ----
        tile = nxt;
        ce   = cen;
        ce0 = ne0; ce1 = ne1;
        ch0 = nh0; ch1 = nh1; ch2 = nh2; ch3 = nh3;
    }
}

extern "C" void kernel_launch(void* const* d_in, const int* in_sizes, int n_in,
                              void* d_out, int out_size, void* d_ws, size_t ws_size,
                              hipStream_t stream) {
    const float* h  = (const float*)d_in[0];
    const float* e  = (const float*)d_in[1];
    const float* W1 = (const float*)d_in[2];
    const float* b1 = (const float*)d_in[3];
    const float* W2 = (const float*)d_in[4];
    const float* b2 = (const float*)d_in[5];
    float* out = (float*)d_out;

    const int E = in_sizes[0] / 16;   // h is [E,16]

    dim3 grid(2048), block(256);
    hipLaunchKernelGGL(msg_kernel, grid, block, 0, stream,
                       h, e, W1, b1, W2, b2, out, E);
}

// Round 6
// 113.718 us; speedup vs baseline: 1.3803x; 1.0984x over previous
//
#include <hip/hip_runtime.h>
#include <hip/hip_bf16.h>

// out[e,i] = sum_j (e@W1+b1)[e, i*16+j] * h[e,j]  +  (e@W2+b2)[e,i]
// One fp16 MFMA GEMM over K=576 per 16-edge tile (18x mfma_f32_16x16x32_f16).
// K-mapping (same placement function on A and B sides):
//   main block kk=0..15, slot s=(lane>>4)*8+t:  (d=s, j=kk)
//     A[r,s] = e[edge_r, s] * h[edge_r, kk]     B[s, i=r] = W1[s*256 + r*16 + kk]
//   block 16: A = e[edge, s],                   B = W2[s*16 + r]
//   block 17: s<16: A=h[edge,s], B=b1[r*16+s]; s==16: A=1, B=b2[r]; else 0
// Hot-loop conversion: v_cvt_pkrtz_f16_f32 (1 instr / 2 values; fp16 RTZ, 10-bit
// mantissa => MORE accurate than bf16 RNE). Products via f32x2 (v_pk_mul_f32).
// NO local arrays anywhere (R2: PromoteAlloca pushed float[16] into LDS).

using f16x8  = __attribute__((ext_vector_type(8))) _Float16;
using fp16v2 = __attribute__((ext_vector_type(2))) __fp16;   // native cvt_pkrtz result type
using f32x4  = __attribute__((ext_vector_type(4))) float;
using f32x2  = __attribute__((ext_vector_type(2))) float;
using u32x4  = __attribute__((ext_vector_type(4))) unsigned int;

// HW packed f32->f16 (round toward zero), 1 VALU op for 2 values
static __device__ __forceinline__ unsigned int pkrtz(float lo, float hi) {
    fp16v2 p = __builtin_amdgcn_cvt_pkrtz(lo, hi);
    return __builtin_bit_cast(unsigned int, p);
}
static __device__ __forceinline__ unsigned int pkrtz2(f32x2 v) { return pkrtz(v[0], v[1]); }

static __device__ __forceinline__ f16x8 mkfrag(unsigned int x0, unsigned int x1,
                                               unsigned int x2, unsigned int x3) {
    u32x4 u = {x0, x1, x2, x3};
    return __builtin_bit_cast(f16x8, u);
}

__global__ void __launch_bounds__(256) msg_kernel(
    const float* __restrict__ hptr, const float* __restrict__ eptr,
    const float* __restrict__ W1,   const float* __restrict__ b1,
    const float* __restrict__ W2,   const float* __restrict__ b2,
    float* __restrict__ out, int E)
{
    const int lane = threadIdx.x & 63;
    const int g    = lane >> 4;        // K-group (0..3); lane's d-range = [g*8, g*8+8)
    const int r    = lane & 15;        // A row (edge-in-tile) == B/D col (output i)

    // ---- B fragments: edge-invariant, built once (RNE casts, one-time cost) ----
    f16x8 Bf[18];
    #pragma unroll
    for (int t = 0; t < 8; ++t) {
        const int d = g * 8 + t;
        const float4* wp = (const float4*)(W1 + (size_t)d * 256 + r * 16);
        const float4 w0 = wp[0], w1 = wp[1], w2 = wp[2], w3 = wp[3];
        Bf[ 0][t] = (_Float16)w0.x; Bf[ 1][t] = (_Float16)w0.y;
        Bf[ 2][t] = (_Float16)w0.z; Bf[ 3][t] = (_Float16)w0.w;
        Bf[ 4][t] = (_Float16)w1.x; Bf[ 5][t] = (_Float16)w1.y;
        Bf[ 6][t] = (_Float16)w1.z; Bf[ 7][t] = (_Float16)w1.w;
        Bf[ 8][t] = (_Float16)w2.x; Bf[ 9][t] = (_Float16)w2.y;
        Bf[10][t] = (_Float16)w2.z; Bf[11][t] = (_Float16)w2.w;
        Bf[12][t] = (_Float16)w3.x; Bf[13][t] = (_Float16)w3.y;
        Bf[14][t] = (_Float16)w3.z; Bf[15][t] = (_Float16)w3.w;
        Bf[16][t] = (_Float16)W2[d * 16 + r];
        float v;
        if (d < 16)       v = b1[r * 16 + d];
        else if (d == 16) v = b2[r];
        else              v = 0.0f;
        Bf[17][t] = (_Float16)v;
    }

    const int ntiles = (E + 15) >> 4;
    const int nwaves = (gridDim.x * blockDim.x) >> 6;
    const int wid    = (blockIdx.x * blockDim.x + threadIdx.x) >> 6;

    int tile = wid;
    if (tile >= ntiles) return;

    int ce = tile * 16 + r;  if (ce >= E) ce = E - 1;
    const float4* ep0 = (const float4*)(eptr + (size_t)ce * 32 + g * 8);
    float4 ce0 = ep0[0], ce1 = ep0[1];
    const float4* hp0 = (const float4*)(hptr + (size_t)ce * 16);
    float4 ch0 = hp0[0], ch1 = hp0[1], ch2 = hp0[2], ch3 = hp0[3];

    while (tile < ntiles) {
        const int nxt = tile + nwaves;
        int cen = (nxt < ntiles) ? (nxt * 16 + r) : ce;
        if (cen >= E) cen = E - 1;

        // ---- next tile's loads, issued before current compute ----
        const float4* epn = (const float4*)(eptr + (size_t)cen * 32 + g * 8);
        float4 ne0 = epn[0], ne1 = epn[1];
        const float4* hpn = (const float4*)(hptr + (size_t)cen * 16);
        float4 nh0 = hpn[0], nh1 = hpn[1], nh2 = hpn[2], nh3 = hpn[3];

        // ---- current tile compute (no arrays; all names static) ----
        const f32x2 e01 = {ce0.x, ce0.y}, e23 = {ce0.z, ce0.w};
        const f32x2 e45 = {ce1.x, ce1.y}, e67 = {ce1.z, ce1.w};

        f32x4 acc0 = {0.0f, 0.0f, 0.0f, 0.0f};
        f32x4 acc1 = {0.0f, 0.0f, 0.0f, 0.0f};

#define MB(KK, S, ACC) { \
        const f32x2 p0 = e01 * (S), p1 = e23 * (S), p2 = e45 * (S), p3 = e67 * (S); \
        const f16x8 a = mkfrag(pkrtz2(p0), pkrtz2(p1), pkrtz2(p2), pkrtz2(p3)); \
        ACC = __builtin_amdgcn_mfma_f32_16x16x32_f16(a, Bf[KK], ACC, 0, 0, 0); }

        MB( 0, ch0.x, acc0) MB( 1, ch0.y, acc1) MB( 2, ch0.z, acc0) MB( 3, ch0.w, acc1)
        MB( 4, ch1.x, acc0) MB( 5, ch1.y, acc1) MB( 6, ch1.z, acc0) MB( 7, ch1.w, acc1)
        MB( 8, ch2.x, acc0) MB( 9, ch2.y, acc1) MB(10, ch2.z, acc0) MB(11, ch2.w, acc1)
        MB(12, ch3.x, acc0) MB(13, ch3.y, acc1) MB(14, ch3.z, acc0) MB(15, ch3.w, acc1)
#undef MB

        {   // block 16: A = e[edge, s]
            const f16x8 a = mkfrag(pkrtz2(e01), pkrtz2(e23), pkrtz2(e45), pkrtz2(e67));
            acc0 = __builtin_amdgcn_mfma_f32_16x16x32_f16(a, Bf[16], acc0, 0, 0, 0);
        }
        {   // block 17: A = h[edge, s] for s<16; 1 at s==16; else 0
            const float v0 = (g == 0) ? ch0.x : (g == 1) ? ch2.x : (g == 2) ? 1.0f : 0.0f;
            const float v1 = (g == 0) ? ch0.y : (g == 1) ? ch2.y : 0.0f;
            const float v2 = (g == 0) ? ch0.z : (g == 1) ? ch2.z : 0.0f;
            const float v3 = (g == 0) ? ch0.w : (g == 1) ? ch2.w : 0.0f;
            const float v4 = (g == 0) ? ch1.x : (g == 1) ? ch3.x : 0.0f;
            const float v5 = (g == 0) ? ch1.y : (g == 1) ? ch3.y : 0.0f;
            const float v6 = (g == 0) ? ch1.z : (g == 1) ? ch3.z : 0.0f;
            const float v7 = (g == 0) ? ch1.w : (g == 1) ? ch3.w : 0.0f;
            const f16x8 a = mkfrag(pkrtz(v0, v1), pkrtz(v2, v3),
                                   pkrtz(v4, v5), pkrtz(v6, v7));
            acc1 = __builtin_amdgcn_mfma_f32_16x16x32_f16(a, Bf[17], acc1, 0, 0, 0);
        }

        // D: col = r = i, row = g*4 + q = edge-in-tile
        const int rowbase = tile * 16 + g * 4;
        #pragma unroll
        for (int q = 0; q < 4; ++q) {
            const int row = rowbase + q;
            if (row < E) out[(size_t)row * 16 + r] = acc0[q] + acc1[q];
        }

        // ---- rotate pipeline ----
        tile = nxt;
        ce   = cen;
        ce0 = ne0; ce1 = ne1;
        ch0 = nh0; ch1 = nh1; ch2 = nh2; ch3 = nh3;
    }
}

extern "C" void kernel_launch(void* const* d_in, const int* in_sizes, int n_in,
                              void* d_out, int out_size, void* d_ws, size_t ws_size,
                              hipStream_t stream) {
    const float* h  = (const float*)d_in[0];
    const float* e  = (const float*)d_in[1];
    const float* W1 = (const float*)d_in[2];
    const float* b1 = (const float*)d_in[3];
    const float* W2 = (const float*)d_in[4];
    const float* b2 = (const float*)d_in[5];
    float* out = (float*)d_out;

    const int E = in_sizes[0] / 16;   // h is [E,16]

    dim3 grid(2048), block(256);
    hipLaunchKernelGGL(msg_kernel, grid, block, 0, stream,
                       h, e, W1, b1, W2, b2, out, E);
}

// Round 7
// 100.301 us; speedup vs baseline: 1.5649x; 1.1338x over previous
//
#include <hip/hip_runtime.h>
#include <hip/hip_bf16.h>

// out[e,i] = sum_j (e@W1+b1)[e, i*16+j] * h[e,j]  +  (e@W2+b2)[e,i]
// One fp16 MFMA GEMM over K=576 per 16-edge tile (18x mfma_f32_16x16x32_f16).
// K-mapping (same placement function on A and B sides):
//   main block kk=0..15, slot s=(lane>>4)*8+t:  (d=s, j=kk)
//     A[r,s] = e[edge_r, s] * h[edge_r, kk]     B[s, i=r] = W1[s*256 + r*16 + kk]
//   block 16: A = e[edge, s],                   B = W2[s*16 + r]
//   block 17: s<16: A=h[edge,s], B=b1[r*16+s]; s==16: A=1, B=b2[r]; else 0
// R6 changes (latency-bound fix):
//   1) B fragments live in LDS (18 KB; 1 ds_read_b128/MFMA at lane*16+kk*1024,
//      conflict-free) -> frees ~72 VGPRs that pinned occupancy.
//   2) 2-deep prefetch (loads for t+2 issued during t) -> load-to-use ~1000cyc
//      > 900cyc HBM latency, vmcnt stall ~0.
//   3) fp16-domain products: e,h converted once/tile (pkrtz), per-block A-frag
//      is 4x v_pk_mul_f16. NO local arrays (R2 LDS-demotion lesson).

using f16x8  = __attribute__((ext_vector_type(8))) _Float16;
using f16x2  = __attribute__((ext_vector_type(2))) _Float16;
using fp16v2 = __attribute__((ext_vector_type(2))) __fp16;   // native cvt_pkrtz type
using f32x4  = __attribute__((ext_vector_type(4))) float;
using u32x4  = __attribute__((ext_vector_type(4))) unsigned int;

static __device__ __forceinline__ unsigned int pkrtz(float lo, float hi) {
    fp16v2 p = __builtin_amdgcn_cvt_pkrtz(lo, hi);
    return __builtin_bit_cast(unsigned int, p);
}
static __device__ __forceinline__ f16x2 u2h(unsigned int u) {
    return __builtin_bit_cast(f16x2, u);
}
static __device__ __forceinline__ unsigned int h2u(f16x2 h) {
    return __builtin_bit_cast(unsigned int, h);
}
static __device__ __forceinline__ unsigned short f2h_bits(float x) {
    _Float16 h = (_Float16)x;                 // RNE scalar cast (one-time build only)
    return __builtin_bit_cast(unsigned short, h);
}

__global__ void __launch_bounds__(256) msg_kernel(
    const float* __restrict__ hptr, const float* __restrict__ eptr,
    const float* __restrict__ W1,   const float* __restrict__ b1,
    const float* __restrict__ W2,   const float* __restrict__ b2,
    float* __restrict__ out, int E)
{
    // B fragment store: [kk=0..17][lane=0..63][t=0..7] fp16, 18 KB.
    __shared__ __align__(16) unsigned short Bs[18 * 64 * 8];

    const int lane = threadIdx.x & 63;
    const int g    = lane >> 4;        // K-group (0..3); lane's d-range = [g*8, g*8+8)
    const int r    = lane & 15;        // A row (edge-in-tile) == B/D col (output i)

    // ---- build B in LDS: wave 0 only, once per block ----
    if (threadIdx.x < 64) {
        #pragma unroll
        for (int t = 0; t < 8; ++t) {
            const int d = g * 8 + t;
            const float4* wp = (const float4*)(W1 + (size_t)d * 256 + r * 16);
            const float4 w0 = wp[0], w1 = wp[1], w2 = wp[2], w3 = wp[3];
            Bs[( 0*64 + lane)*8 + t] = f2h_bits(w0.x);
            Bs[( 1*64 + lane)*8 + t] = f2h_bits(w0.y);
            Bs[( 2*64 + lane)*8 + t] = f2h_bits(w0.z);
            Bs[( 3*64 + lane)*8 + t] = f2h_bits(w0.w);
            Bs[( 4*64 + lane)*8 + t] = f2h_bits(w1.x);
            Bs[( 5*64 + lane)*8 + t] = f2h_bits(w1.y);
            Bs[( 6*64 + lane)*8 + t] = f2h_bits(w1.z);
            Bs[( 7*64 + lane)*8 + t] = f2h_bits(w1.w);
            Bs[( 8*64 + lane)*8 + t] = f2h_bits(w2.x);
            Bs[( 9*64 + lane)*8 + t] = f2h_bits(w2.y);
            Bs[(10*64 + lane)*8 + t] = f2h_bits(w2.z);
            Bs[(11*64 + lane)*8 + t] = f2h_bits(w2.w);
            Bs[(12*64 + lane)*8 + t] = f2h_bits(w3.x);
            Bs[(13*64 + lane)*8 + t] = f2h_bits(w3.y);
            Bs[(14*64 + lane)*8 + t] = f2h_bits(w3.z);
            Bs[(15*64 + lane)*8 + t] = f2h_bits(w3.w);
            Bs[(16*64 + lane)*8 + t] = f2h_bits(W2[d * 16 + r]);
            float v;
            if (d < 16)       v = b1[r * 16 + d];
            else if (d == 16) v = b2[r];
            else              v = 0.0f;
            Bs[(17*64 + lane)*8 + t] = f2h_bits(v);
        }
    }
    __syncthreads();   // only barrier in the kernel

    const int ntiles = (E + 15) >> 4;
    const int nwaves = (gridDim.x * blockDim.x) >> 6;
    const int wid    = (blockIdx.x * blockDim.x + threadIdx.x) >> 6;
    if (wid >= ntiles) return;

    const unsigned short* bsl = &Bs[lane * 8];   // per-lane base; block kk at +kk*512

#define LDSB(KK) __builtin_bit_cast(f16x8, *reinterpret_cast<const u32x4*>(bsl + (KK) * 512))

#define LOADT(T, E0, E1, H0, H1, H2, H3) { \
        int tt = (T); if (tt >= ntiles) tt = ntiles - 1; \
        int cc = tt * 16 + r; if (cc >= E) cc = E - 1; \
        const float4* ep_ = (const float4*)(eptr + (size_t)cc * 32 + g * 8); \
        E0 = ep_[0]; E1 = ep_[1]; \
        const float4* hp_ = (const float4*)(hptr + (size_t)cc * 16); \
        H0 = hp_[0]; H1 = hp_[1]; H2 = hp_[2]; H3 = hp_[3]; }

    // BODY: convert stage regs -> fp16, prefetch t+2*nw into same stage regs,
    // run 18 MFMAs, store. All names static.
#define BODY(T, E0, E1, H0, H1, H2, H3) { \
        /* convert current tile (waits on its loads, issued 2 iters ago) */ \
        const unsigned int eP0 = pkrtz(E0.x, E0.y), eP1 = pkrtz(E0.z, E0.w); \
        const unsigned int eP2 = pkrtz(E1.x, E1.y), eP3 = pkrtz(E1.z, E1.w); \
        const unsigned int hB0  = pkrtz(H0.x, H0.x), hB1  = pkrtz(H0.y, H0.y); \
        const unsigned int hB2  = pkrtz(H0.z, H0.z), hB3  = pkrtz(H0.w, H0.w); \
        const unsigned int hB4  = pkrtz(H1.x, H1.x), hB5  = pkrtz(H1.y, H1.y); \
        const unsigned int hB6  = pkrtz(H1.z, H1.z), hB7  = pkrtz(H1.w, H1.w); \
        const unsigned int hB8  = pkrtz(H2.x, H2.x), hB9  = pkrtz(H2.y, H2.y); \
        const unsigned int hB10 = pkrtz(H2.z, H2.z), hB11 = pkrtz(H2.w, H2.w); \
        const unsigned int hB12 = pkrtz(H3.x, H3.x), hB13 = pkrtz(H3.y, H3.y); \
        const unsigned int hB14 = pkrtz(H3.z, H3.z), hB15 = pkrtz(H3.w, H3.w); \
        /* block-17 A fragment from f32 h (g-select), before raw regs die */ \
        const float v0_ = (g == 0) ? H0.x : (g == 1) ? H2.x : (g == 2) ? 1.0f : 0.0f; \
        const float v1_ = (g == 0) ? H0.y : (g == 1) ? H2.y : 0.0f; \
        const float v2_ = (g == 0) ? H0.z : (g == 1) ? H2.z : 0.0f; \
        const float v3_ = (g == 0) ? H0.w : (g == 1) ? H2.w : 0.0f; \
        const float v4_ = (g == 0) ? H1.x : (g == 1) ? H3.x : 0.0f; \
        const float v5_ = (g == 0) ? H1.y : (g == 1) ? H3.y : 0.0f; \
        const float v6_ = (g == 0) ? H1.z : (g == 1) ? H3.z : 0.0f; \
        const float v7_ = (g == 0) ? H1.w : (g == 1) ? H3.w : 0.0f; \
        const unsigned int a17_0 = pkrtz(v0_, v1_), a17_1 = pkrtz(v2_, v3_); \
        const unsigned int a17_2 = pkrtz(v4_, v5_), a17_3 = pkrtz(v6_, v7_); \
        /* prefetch t+2*nw into this stage's regs (freed by conversion) */ \
        LOADT((T) + 2 * nwaves, E0, E1, H0, H1, H2, H3); \
        f32x4 acc0 = {0.0f, 0.0f, 0.0f, 0.0f}; \
        f32x4 acc1 = {0.0f, 0.0f, 0.0f, 0.0f}; \
        MB( 0, hB0,  acc0) MB( 1, hB1,  acc1) MB( 2, hB2,  acc0) MB( 3, hB3,  acc1) \
        MB( 4, hB4,  acc0) MB( 5, hB5,  acc1) MB( 6, hB6,  acc0) MB( 7, hB7,  acc1) \
        MB( 8, hB8,  acc0) MB( 9, hB9,  acc1) MB(10, hB10, acc0) MB(11, hB11, acc1) \
        MB(12, hB12, acc0) MB(13, hB13, acc1) MB(14, hB14, acc0) MB(15, hB15, acc1) \
        {   /* block 16: A = e-pack directly */ \
            u32x4 u_ = {eP0, eP1, eP2, eP3}; \
            acc0 = __builtin_amdgcn_mfma_f32_16x16x32_f16( \
                __builtin_bit_cast(f16x8, u_), LDSB(16), acc0, 0, 0, 0); \
        } \
        {   /* block 17 */ \
            u32x4 u_ = {a17_0, a17_1, a17_2, a17_3}; \
            acc1 = __builtin_amdgcn_mfma_f32_16x16x32_f16( \
                __builtin_bit_cast(f16x8, u_), LDSB(17), acc1, 0, 0, 0); \
        } \
        const int rowbase = (T) * 16 + g * 4; \
        const int row0 = rowbase, row1 = rowbase + 1, row2 = rowbase + 2, row3 = rowbase + 3; \
        if (row0 < E) out[(size_t)row0 * 16 + r] = acc0[0] + acc1[0]; \
        if (row1 < E) out[(size_t)row1 * 16 + r] = acc0[1] + acc1[1]; \
        if (row2 < E) out[(size_t)row2 * 16 + r] = acc0[2] + acc1[2]; \
        if (row3 < E) out[(size_t)row3 * 16 + r] = acc0[3] + acc1[3]; }

#define MB(KK, HB, ACC) { \
        const f16x2 hh_ = u2h(HB); \
        u32x4 u_ = {h2u(hh_ * u2h(eP0)), h2u(hh_ * u2h(eP1)), \
                    h2u(hh_ * u2h(eP2)), h2u(hh_ * u2h(eP3))}; \
        ACC = __builtin_amdgcn_mfma_f32_16x16x32_f16( \
            __builtin_bit_cast(f16x8, u_), LDSB(KK), ACC, 0, 0, 0); }

    // ---- 2-deep pipeline, unrolled by 2 (stages alternate; no swap moves) ----
    float4 aE0, aE1, aH0, aH1, aH2, aH3;   // stage A raw f32
    float4 bE0, bE1, bH0, bH1, bH2, bH3;   // stage B raw f32

    int t = wid;
    LOADT(t,          aE0, aE1, aH0, aH1, aH2, aH3);
    LOADT(t + nwaves, bE0, bE1, bH0, bH1, bH2, bH3);

    while (true) {
        BODY(t, aE0, aE1, aH0, aH1, aH2, aH3);
        t += nwaves;
        if (t >= ntiles) break;
        BODY(t, bE0, bE1, bH0, bH1, bH2, bH3);
        t += nwaves;
        if (t >= ntiles) break;
    }

#undef MB
#undef BODY
#undef LOADT
#undef LDSB
}

extern "C" void kernel_launch(void* const* d_in, const int* in_sizes, int n_in,
                              void* d_out, int out_size, void* d_ws, size_t ws_size,
                              hipStream_t stream) {
    const float* h  = (const float*)d_in[0];
    const float* e  = (const float*)d_in[1];
    const float* W1 = (const float*)d_in[2];
    const float* b1 = (const float*)d_in[3];
    const float* W2 = (const float*)d_in[4];
    const float* b2 = (const float*)d_in[5];
    float* out = (float*)d_out;

    const int E = in_sizes[0] / 16;   // h is [E,16]

    dim3 grid(2048), block(256);
    hipLaunchKernelGGL(msg_kernel, grid, block, 0, stream,
                       h, e, W1, b1, W2, b2, out, E);
}